// Round 6
// baseline (1186.929 us; speedup 1.0000x reference)
//
#include <hip/hip_runtime.h>
#include <cstdint>
#include <cstddef>

// ---------------- types & helpers ----------------
typedef __attribute__((ext_vector_type(4))) float floatx4;
typedef __attribute__((ext_vector_type(8))) short short8;

__device__ __forceinline__ short f2bf(float x) {
  union { float f; unsigned u; } c; c.f = x;
  unsigned r = (c.u + 0x7FFFu + ((c.u >> 16) & 1u)) >> 16;  // RNE
  return (short)r;
}

__device__ __forceinline__ float bf2f(short x) {
  union { unsigned u; float f; } c; c.u = ((unsigned)(unsigned short)x) << 16;
  return c.f;
}

__device__ __forceinline__ floatx4 mfma16(short8 a, short8 b, floatx4 c) {
  return __builtin_amdgcn_mfma_f32_16x16x32_bf16(a, b, c, 0, 0, 0);
}

// async global->LDS, 16B per lane; LDS dest is wave-uniform base + lane*16
template <typename T>
__device__ __forceinline__ void gl_lds16(const T* g, T* l) {
  __builtin_amdgcn_global_load_lds(
      (__attribute__((address_space(1))) void*)g,
      (__attribute__((address_space(3))) void*)l, 16, 0, 0);
}

#define MEMFENCE asm volatile("" ::: "memory")
#define WAITV8 asm volatile("s_waitcnt vmcnt(8)" ::: "memory")
#define WAITV2 asm volatile("s_waitcnt vmcnt(2)" ::: "memory")
#define WAITV0 asm volatile("s_waitcnt vmcnt(0)" ::: "memory")

// ---------------- rmsnorm (+silu) with optional replicate-pad ----------------
template <bool PAD, bool SILU>
__global__ __launch_bounds__(256) void norm_kernel(const float* __restrict__ src,
                                                   const float* __restrict__ gamma,
                                                   short* __restrict__ dst) {
  const int tid = threadIdx.x;
  const int wv = tid >> 6, lane = tid & 63;
  const int id = blockIdx.x * 4 + wv;
  int srow;
  if (PAD) {
    int tp = id / 1156, rem = id - tp * 1156;
    int hp = rem / 34, wp = rem - hp * 34;
    int t = tp - 2; t = t < 0 ? 0 : t;
    int h = hp - 1; h = h < 0 ? 0 : (h > 31 ? 31 : h);
    int w = wp - 1; w = w < 0 ? 0 : (w > 31 ? 31 : w);
    srow = (t << 10) + (h << 5) + w;
  } else {
    srow = id;
  }
  const float* sp = src + (size_t)srow * 512 + lane * 8;
  float4 v0 = *(const float4*)sp;
  float4 v1 = *(const float4*)(sp + 4);
  float a[8] = {v0.x, v0.y, v0.z, v0.w, v1.x, v1.y, v1.z, v1.w};
  float ss = 0.f;
#pragma unroll
  for (int i = 0; i < 8; ++i) ss += a[i] * a[i];
#pragma unroll
  for (int off = 32; off > 0; off >>= 1) ss += __shfl_xor(ss, off);
  const float scale = 22.627416997969522f / (sqrtf(ss) + 1e-8f);  // sqrt(512)/(||x||+eps)
  const float* gp = gamma + lane * 8;
  float4 g0 = *(const float4*)gp;
  float4 g1 = *(const float4*)(gp + 4);
  float g[8] = {g0.x, g0.y, g0.z, g0.w, g1.x, g1.y, g1.z, g1.w};
  short8 ov;
#pragma unroll
  for (int i = 0; i < 8; ++i) {
    float y = a[i] * scale * g[i];
    if (SILU) y = y / (1.f + __expf(-y));
    ov[i] = f2bf(y);
  }
  *(short8*)(dst + (size_t)id * 512 + lane * 8) = ov;
}

// ---------------- fused split-K combine (4 partials) + rmsnorm + silu + replicate-pad ----------------
__global__ __launch_bounds__(256) void combine_norm(const float* __restrict__ P0,
                                                    const float* __restrict__ P1,
                                                    const float* __restrict__ P2,
                                                    const float* __restrict__ P3,
                                                    const float* __restrict__ bias,
                                                    const float* __restrict__ gamma,
                                                    short* __restrict__ dst) {
  const int tid = threadIdx.x;
  const int wv = tid >> 6, lane = tid & 63;
  const int id = blockIdx.x * 4 + wv;
  int tp = id / 1156, rem = id - tp * 1156;
  int hp = rem / 34, wp = rem - hp * 34;
  int t = tp - 2; t = t < 0 ? 0 : t;
  int h = hp - 1; h = h < 0 ? 0 : (h > 31 ? 31 : h);
  int w = wp - 1; w = w < 0 ? 0 : (w > 31 ? 31 : w);
  const size_t base = (size_t)((t << 10) + (h << 5) + w) * 512 + lane * 8;
  float a[8];
  {
    float4 a0 = *(const float4*)(P0 + base), a1 = *(const float4*)(P0 + base + 4);
    float4 b0 = *(const float4*)(P1 + base), b1 = *(const float4*)(P1 + base + 4);
    float4 c0 = *(const float4*)(P2 + base), c1 = *(const float4*)(P2 + base + 4);
    float4 d0 = *(const float4*)(P3 + base), d1 = *(const float4*)(P3 + base + 4);
    float4 z0 = *(const float4*)(bias + lane * 8), z1 = *(const float4*)(bias + lane * 8 + 4);
    a[0] = a0.x + b0.x + c0.x + d0.x + z0.x;
    a[1] = a0.y + b0.y + c0.y + d0.y + z0.y;
    a[2] = a0.z + b0.z + c0.z + d0.z + z0.z;
    a[3] = a0.w + b0.w + c0.w + d0.w + z0.w;
    a[4] = a1.x + b1.x + c1.x + d1.x + z1.x;
    a[5] = a1.y + b1.y + c1.y + d1.y + z1.y;
    a[6] = a1.z + b1.z + c1.z + d1.z + z1.z;
    a[7] = a1.w + b1.w + c1.w + d1.w + z1.w;
  }
  float ss = 0.f;
#pragma unroll
  for (int i = 0; i < 8; ++i) ss += a[i] * a[i];
#pragma unroll
  for (int off = 32; off > 0; off >>= 1) ss += __shfl_xor(ss, off);
  const float scale = 22.627416997969522f / (sqrtf(ss) + 1e-8f);
  float4 g0 = *(const float4*)(gamma + lane * 8), g1 = *(const float4*)(gamma + lane * 8 + 4);
  float g[8] = {g0.x, g0.y, g0.z, g0.w, g1.x, g1.y, g1.z, g1.w};
  short8 ov;
#pragma unroll
  for (int i = 0; i < 8; ++i) {
    float y = a[i] * scale * g[i];
    y = y / (1.f + __expf(-y));
    ov[i] = f2bf(y);
  }
  *(short8*)(dst + (size_t)id * 512 + lane * 8) = ov;
}

// ---------------- weight transpose fp32 [R][C] -> bf16 [C][R] ----------------
__global__ __launch_bounds__(256) void transpose_w(const float* __restrict__ src,
                                                   short* __restrict__ dst, int R, int C) {
  __shared__ float t[32][33];
  const int tx = threadIdx.x & 31, ty = threadIdx.x >> 5;
  const int r0 = (int)blockIdx.x << 5, c0 = (int)blockIdx.y << 5;
#pragma unroll
  for (int i = 0; i < 4; ++i)
    t[ty + i * 8][tx] = src[(size_t)(r0 + ty + i * 8) * C + c0 + tx];
  __syncthreads();
#pragma unroll
  for (int i = 0; i < 4; ++i)
    dst[(size_t)(c0 + ty + i * 8) * R + r0 + tx] = f2bf(t[tx][ty + i * 8]);
}

// ---------------- implicit-GEMM causal conv3d: 256x256 tile, 8 waves, 4-phase ----------------
// split-K 4 -> grid (32,2,4) = 256 blocks = 1/CU, no tail. BK=64, dbuf LDS 128KB.
// Per K-step: 4 phases x {stage 2 gl_lds16 for t+1 | ds_read A-quadrant | 16 MFMA
// in setprio}. vmcnt(2) ONCE per step at phase 0 (counted, never drained in-loop).
// LDS rows are 128B (64ch x 2B): slot(16B) XOR-swizzled by row&7 -> conflict-free
// ds_read_b128; gl_lds16 writes linearly so the swizzle is realized by permuting
// the per-lane GLOBAL source; reads apply the same XOR (both-sides involution).
__global__ __launch_bounds__(512, 2) void conv_gemm8(const short* __restrict__ Xp,
                                                     const short* __restrict__ WT,
                                                     float* __restrict__ P0,
                                                     float* __restrict__ P1,
                                                     float* __restrict__ P2,
                                                     float* __restrict__ P3) {
  __shared__ __attribute__((aligned(16))) short Alds[2][16384];
  __shared__ __attribute__((aligned(16))) short Blds[2][16384];
  const int tid = threadIdx.x;
  const int wid = tid >> 6, lane = tid & 63;
  const int m0 = (int)blockIdx.x << 8, n0 = (int)blockIdx.y << 8;
  const int z = blockIdx.z;
  float* __restrict__ dst = z == 0 ? P0 : (z == 1 ? P1 : (z == 2 ? P2 : P3));
  const int wm = (wid >> 2) << 7, wn = (wid & 3) << 6;  // wave 2M x 4N -> 128x64 out

  // staging constants: thread covers (row = part*64 + tid/8, phys slot = tid&7);
  // fetch logical ch-slot = phys ^ (row&7)
  const int logslot = (tid & 7) ^ ((tid >> 3) & 7);
  int aoffA[4], boffB[4];
#pragma unroll
  for (int q = 0; q < 4; ++q) {
    const int m = m0 + q * 64 + (tid >> 3);
    const int t = m >> 10, h = (m >> 5) & 31, w = m & 31;
    aoffA[q] = (t * 1156 + h * 34 + w) * 512 + logslot * 8;
    boffB[q] = (n0 + q * 64 + (tid >> 3)) * 13824 + logslot * 8;
  }
  const int lwb = wid * 512;  // per-wave LDS dest offset (shorts) within a part

  // frag-read constants: row = base + (lane&15); phys slot = logical ^ (lane&7)
  const int frow = lane & 15;
  const int fslot = lane >> 4;  // 0..3
  const int sx = lane & 7;

  floatx4 acc[4][2][4];
#pragma unroll
  for (int p = 0; p < 4; ++p)
#pragma unroll
    for (int i = 0; i < 2; ++i)
#pragma unroll
      for (int j = 0; j < 4; ++j) acc[p][i][j] = 0.f;

  const int k0g = z * 54;  // 216 K-steps of 64 over 27 taps x 512cin, split 4

  auto tapoff_of = [&](int kkg) {
    const int tap = kkg >> 3;
    const int dt = tap / 9;
    const int r9 = tap - dt * 9;
    const int dh = r9 / 3;
    const int dw = r9 - dh * 3;
    return (dt * 1156 + dh * 34 + dw) * 512 + ((kkg & 7) << 6);
  };

  // prologue: stage all 8 parts of step 0
  {
    const int to = tapoff_of(k0g);
#pragma unroll
    for (int q = 0; q < 4; ++q) {
      gl_lds16(Xp + aoffA[q] + to, &Alds[0][q * 4096 + lwb]);
      gl_lds16(WT + boffB[q] + (k0g << 6), &Blds[0][q * 4096 + lwb]);
    }
  }

  for (int kk = 0; kk < 54; ++kk) {
    const int buf = kk & 1;
    const bool nx = (kk + 1 < 54);
    const int kng = k0g + kk + 1;
    const int ton = nx ? tapoff_of(kng) : 0;
    short8 bfr[4][2];
#pragma unroll
    for (int p = 0; p < 4; ++p) {
      if (p == 0) {
        if (nx) {
          gl_lds16(Xp + aoffA[0] + ton, &Alds[buf ^ 1][lwb]);
          gl_lds16(Xp + aoffA[1] + ton, &Alds[buf ^ 1][4096 + lwb]);
          WAITV2;  // retire this step's 8 loads; keep 2 in flight
        } else {
          WAITV0;
        }
      } else if (nx) {
        if (p == 1) {
          gl_lds16(Xp + aoffA[2] + ton, &Alds[buf ^ 1][8192 + lwb]);
          gl_lds16(Xp + aoffA[3] + ton, &Alds[buf ^ 1][12288 + lwb]);
        } else if (p == 2) {
          gl_lds16(WT + boffB[0] + (kng << 6), &Blds[buf ^ 1][lwb]);
          gl_lds16(WT + boffB[1] + (kng << 6), &Blds[buf ^ 1][4096 + lwb]);
        } else {
          gl_lds16(WT + boffB[2] + (kng << 6), &Blds[buf ^ 1][8192 + lwb]);
          gl_lds16(WT + boffB[3] + (kng << 6), &Blds[buf ^ 1][12288 + lwb]);
        }
      }
      MEMFENCE;
      __builtin_amdgcn_s_barrier();
      MEMFENCE;
      if (p == 0) {
#pragma unroll
        for (int fj = 0; fj < 4; ++fj)
#pragma unroll
          for (int ks = 0; ks < 2; ++ks) {
            const int row = wn + fj * 16 + frow;
            bfr[fj][ks] =
                *(const short8*)&Blds[buf][row * 64 + (((ks << 2) + fslot) ^ sx) * 8];
          }
      }
      short8 afr[2][2];
#pragma unroll
      for (int fi = 0; fi < 2; ++fi)
#pragma unroll
        for (int ks = 0; ks < 2; ++ks) {
          const int row = wm + p * 32 + fi * 16 + frow;
          afr[fi][ks] =
              *(const short8*)&Alds[buf][row * 64 + (((ks << 2) + fslot) ^ sx) * 8];
        }
      __builtin_amdgcn_s_setprio(1);
#pragma unroll
      for (int fi = 0; fi < 2; ++fi)
#pragma unroll
        for (int fj = 0; fj < 4; ++fj)
#pragma unroll
          for (int ks = 0; ks < 2; ++ks)
            acc[p][fi][fj] = mfma16(afr[fi][ks], bfr[fj][ks], acc[p][fi][fj]);
      __builtin_amdgcn_s_setprio(0);
      MEMFENCE;
      __builtin_amdgcn_s_barrier();
      MEMFENCE;
    }
  }

  // epilogue: C/D mapping col = lane&15, row = (lane>>4)*4 + r
#pragma unroll
  for (int p = 0; p < 4; ++p)
#pragma unroll
    for (int fi = 0; fi < 2; ++fi) {
      const int rb = m0 + wm + p * 32 + fi * 16 + (lane >> 4) * 4;
#pragma unroll
      for (int fj = 0; fj < 4; ++fj) {
        const int col = n0 + wn + fj * 16 + (lane & 15);
#pragma unroll
        for (int r = 0; r < 4; ++r)
          dst[(size_t)(rb + r) * 512 + col] = acc[p][fi][fj][r];
      }
    }
}

template <bool HAS_RES>
__global__ __launch_bounds__(256) void conv_combine(const float* __restrict__ P0,
                                                    const float* __restrict__ P1,
                                                    const float* __restrict__ P2,
                                                    const float* __restrict__ P3,
                                                    const float* __restrict__ bias,
                                                    const float* __restrict__ res,
                                                    float* __restrict__ out) {
  const size_t i = ((size_t)blockIdx.x * 256 + threadIdx.x) * 4;
  float4 a = *(const float4*)(P0 + i);
  float4 b = *(const float4*)(P1 + i);
  float4 c = *(const float4*)(P2 + i);
  float4 d = *(const float4*)(P3 + i);
  float4 bz = *(const float4*)(bias + (int)(i & 511));
  float4 r;
  r.x = a.x + b.x + c.x + d.x + bz.x;
  r.y = a.y + b.y + c.y + d.y + bz.y;
  r.z = a.z + b.z + c.z + d.z + bz.z;
  r.w = a.w + b.w + c.w + d.w + bz.w;
  if (HAS_RES) {
    float4 rs = *(const float4*)(res + i);
    r.x += rs.x; r.y += rs.y; r.z += rs.z; r.w += rs.w;
  }
  *(float4*)(out + i) = r;
}

// ---------------- generic GEMM  C = A(MxK) * BT(NxK)^T, dbuf prefetch ----------------
// Slot-XOR LDS swizzle (R2). EPI=0: QKV — Q row-major bf16; K,V pre-swizzled:
//   K tile offset(key,c) = (c>>5)*1024 + ((c>>3)&3)*256 + key*8 + (c&7)
//   V tile offset(key,c) = ((key>>3)&3)*4096 + c*8 + (key&7)
// EPI=1: fp32 out = acc + bias + res (proj + identity; in-place-safe).
template <int EPI>
__global__ __launch_bounds__(256) void gemm_bt(const short* __restrict__ A,
                                               const short* __restrict__ BT, int kdim,
                                               const float* __restrict__ b0,
                                               const float* __restrict__ b1,
                                               const float* __restrict__ b2,
                                               short* __restrict__ o0,
                                               short* __restrict__ o1,
                                               short* __restrict__ o2,
                                               float* oF, const float* res) {
  __shared__ __attribute__((aligned(16))) short Alds[2][4096];
  __shared__ __attribute__((aligned(16))) short Blds[2][4096];
  const int tid = threadIdx.x;
  const int wv = tid >> 6, lane = tid & 63;
  const int m0 = (int)blockIdx.x << 7, n0 = (int)blockIdx.y << 7;
  const int swz = (((lane & 3) ^ ((lane >> 3) & 3)) << 3);
  int aoff[2], boff[2];
#pragma unroll
  for (int j = 0; j < 2; ++j) {
    const int chunk = wv * 2 + j;
    aoff[j] = (m0 + chunk * 16 + (lane >> 2)) * kdim + swz;
    boff[j] = (n0 + chunk * 16 + (lane >> 2)) * kdim + swz;
  }
  const int wm = (wv & 1) << 6, wn = (wv >> 1) << 6;
  floatx4 acc[4][4];
#pragma unroll
  for (int i = 0; i < 4; ++i)
#pragma unroll
    for (int j = 0; j < 4; ++j) acc[i][j] = 0.f;
  const int la = (lane & 15) * 32 + ((((lane >> 4) ^ ((lane >> 1) & 3))) << 3);
  const int kiters = kdim >> 5;

  auto stage = [&](int kk, int buf) {
#pragma unroll
    for (int j = 0; j < 2; ++j) {
      const int chunk = wv * 2 + j;
      gl_lds16(A + aoff[j] + (kk << 5), &Alds[buf][chunk * 512]);
      gl_lds16(BT + boff[j] + (kk << 5), &Blds[buf][chunk * 512]);
    }
  };

  stage(0, 0);
  for (int kk = 0; kk < kiters; ++kk) {
    const int cur = kk & 1;
    __syncthreads();
    if (kk + 1 < kiters) stage(kk + 1, cur ^ 1);
    short8 af[4], bf[4];
#pragma unroll
    for (int i = 0; i < 4; ++i) af[i] = *(const short8*)&Alds[cur][(wm + i * 16) * 32 + la];
#pragma unroll
    for (int j = 0; j < 4; ++j) bf[j] = *(const short8*)&Blds[cur][(wn + j * 16) * 32 + la];
#pragma unroll
    for (int i = 0; i < 4; ++i)
#pragma unroll
      for (int j = 0; j < 4; ++j) acc[i][j] = mfma16(af[i], bf[j], acc[i][j]);
  }

  const int rbase = m0 + wm + (lane >> 4) * 4;
#pragma unroll
  for (int i = 0; i < 4; ++i) {
    const int row = rbase + i * 16;
#pragma unroll
    for (int j = 0; j < 4; ++j) {
      const int col = n0 + wn + j * 16 + (lane & 15);
      if (EPI == 0) {
        const int sel = col >> 9;
        const int c = col & 511;
        const float* bp = sel == 0 ? b0 : (sel == 1 ? b1 : b2);
        const float bz = bp[c];
#pragma unroll
        for (int r = 0; r < 4; ++r) {
          const int rr = row + r;
          const short v = f2bf(acc[i][j][r] + bz);
          if (sel == 0) {
            o0[(size_t)rr * 512 + c] = v;
          } else if (sel == 1) {
            o1[(size_t)(rr >> 5) * 16384 + ((c >> 5) << 10) + (((c >> 3) & 3) << 8) +
               ((rr & 31) << 3) + (c & 7)] = v;
          } else {
            o2[(size_t)(rr >> 5) * 16384 + (((rr >> 3) & 3) << 12) + (c << 3) + (rr & 7)] = v;
          }
        }
      } else {
        const float bz = b0[col];
#pragma unroll
        for (int r = 0; r < 4; ++r) {
          const size_t idx = (size_t)(row + r) * 512 + col;
          oF[idx] = acc[i][j][r] + bz + res[idx];
        }
      }
    }
  }
}

// ---------------- split-K flash attention partials ----------------
// block = 256 thr (4 waves) = 64 q x one 1024-key chunk; grid 576.
// LDS diet for 3 blocks/CU (53248 B): K staged in d-HALVES (16KB buffer; Ksw
// layout is already contiguous per 256-ch half), V full 32KB, P 4KB. 576 blocks
// fit one occupancy round (768 slots) -> no 64-block tail round.
// Pipeline per kt: WAITV8 retires Kd0 (V still in flight) | QK kc0-7 | stage Kd1
// | WAITV0+bar (publishes V too; ~L2-latency drain on Kd1 is the accepted cost)
// | QK kc8-15 | stage Kd0(t+1) | softmax | PV | bar | stage V(t+1).
__global__ __launch_bounds__(256, 3) void attn_partial(const short* __restrict__ Q,
                                                       const short* __restrict__ Ksw,
                                                       const short* __restrict__ Vsw,
                                                       short* __restrict__ OpA,
                                                       short* __restrict__ OpB,
                                                       float* __restrict__ Lp) {
  __shared__ __attribute__((aligned(16))) short Klds[8192];   // 16KB: one d-half
  __shared__ __attribute__((aligned(16))) short Vlds[16384];  // 32KB
  __shared__ __attribute__((aligned(16))) short Plds[4][512];
  const int tid = threadIdx.x;
  const int wv = tid >> 6, lane = tid & 63;
  const int cl = lane & 15, quad = lane >> 4;
  // XCD-clustered mapping: xcd = bid & 7 (HW round-robin heuristic).
  const int bid = (int)blockIdx.x;
  const int x8 = bid & 7, jj = bid >> 3;
  int y, qb;
  if (jj < 64) {
    y = x8 + ((jj >> 4) << 3);
    qb = jj & 15;
  } else {
    const int L = x8 * 8 + (jj - 64);
    y = 32 + (L >> 4);
    qb = L & 15;
  }
  int f = 0;
  while ((f + 1) * (f + 2) / 2 <= y) ++f;
  const int chunk = y - f * (f + 1) / 2;
  const int pidx = y * 16 + qb;
  const int q0 = (f << 10) + (qb << 6);

  short8 qf[16];
  {
    const short* qp = Q + (size_t)(q0 + wv * 16 + cl) * 512 + quad * 8;
#pragma unroll
    for (int kc = 0; kc < 16; ++kc) qf[kc] = *(const short8*)(qp + kc * 32);
  }
  floatx4 o[32];
#pragma unroll
  for (int i = 0; i < 32; ++i) o[i] = 0.f;
  float lr[4] = {0.f, 0.f, 0.f, 0.f};
  const float c1 = 0.063758716f;  // log2(e)/sqrt(512)
  const short* klb = Klds + quad * 256 + cl * 8;
  const short* vlb = Vlds + quad * 4096 + cl * 8;
  const int swr = ((cl >> 1) & 3) << 3;

  // stage one 256-ch d-half of the 32-key K tile (16KB, 4 loads/wave)
  auto stageKh = [&](int kt, int half) {
    const size_t tb = (size_t)((chunk << 5) + kt) * 16384 + (half << 13);
#pragma unroll
    for (int j = 0; j < 4; ++j) {
      const int row = (j * 4 + wv) << 9;
      gl_lds16(Ksw + tb + row + lane * 8, &Klds[row]);
    }
  };
  auto stageV = [&](int kt) {
    const size_t tb = (size_t)((chunk << 5) + kt) * 16384;
#pragma unroll
    for (int j = 0; j < 8; ++j) {
      const int row = (j * 4 + wv) << 9;
      gl_lds16(Vsw + tb + row + lane * 8, &Vlds[row]);
    }
  };

  // prologue: [Kd0(0):4, V(0):8] in flight per wave
  stageKh(0, 0);
  stageV(0);

  for (int kt = 0; kt < 32; ++kt) {
    // retire Kd0(kt) (oldest 4 of 12); V(kt) stays in flight
    WAITV8;
    __builtin_amdgcn_s_barrier();
    MEMFENCE;

    floatx4 s0 = 0.f, s1 = 0.f;
    __builtin_amdgcn_s_setprio(1);
#pragma unroll
    for (int kc = 0; kc < 8; ++kc) {
      short8 k0 = *(const short8*)(klb + kc * 1024);
      short8 k1 = *(const short8*)(klb + kc * 1024 + 128);
      s0 = mfma16(qf[kc], k0, s0);
      s1 = mfma16(qf[kc], k1, s1);
    }
    __builtin_amdgcn_s_setprio(0);

    MEMFENCE;
    __builtin_amdgcn_s_barrier();  // all waves done reading Kd0
    MEMFENCE;
    stageKh(kt, 1);  // -> [V(kt):8, Kd1(kt):4]

    // Kd1 is newest -> must drain fully; also publishes V(kt) for PV.
    WAITV0;
    __builtin_amdgcn_s_barrier();
    MEMFENCE;

    __builtin_amdgcn_s_setprio(1);
#pragma unroll
    for (int kc = 8; kc < 16; ++kc) {
      short8 k0 = *(const short8*)(klb + (kc - 8) * 1024);
      short8 k1 = *(const short8*)(klb + (kc - 8) * 1024 + 128);
      s0 = mfma16(qf[kc], k0, s0);
      s1 = mfma16(qf[kc], k1, s1);
    }
    __builtin_amdgcn_s_setprio(0);

    MEMFENCE;
    __builtin_amdgcn_s_barrier();  // all waves done reading Kd1
    MEMFENCE;
    if (kt + 1 < 32) stageKh(kt + 1, 0);  // flies under softmax + PV

#pragma unroll
    for (int r = 0; r < 4; ++r) {
      const float p0 = exp2f(s0[r] * c1), p1 = exp2f(s1[r] * c1);
      lr[r] += p0 + p1;  // per-lane partial; row-sum deferred to epilogue
      const int qlr = quad * 4 + r;
      const int sw = ((qlr >> 1) & 3) << 3;
      const int oi = qlr * 32 + (cl ^ sw);
      Plds[wv][oi] = f2bf(p0);
      Plds[wv][oi ^ 16] = f2bf(p1);
    }

    // V(kt) already resident & published (WAITV0 + barrier above).
    const short8 pf = *(const short8*)&Plds[wv][cl * 32 + ((quad << 3) ^ swr)];
    __builtin_amdgcn_s_setprio(1);
#pragma unroll
    for (int cn = 0; cn < 32; ++cn) {
      const short8 vf = *(const short8*)(vlb + cn * 128);
      o[cn] = mfma16(pf, vf, o[cn]);
    }
    __builtin_amdgcn_s_setprio(0);

    MEMFENCE;
    __builtin_amdgcn_s_barrier();  // all waves done reading Vlds
    MEMFENCE;
    if (kt + 1 < 32) stageV(kt + 1);  // flies under next QK
  }

#pragma unroll
  for (int r = 0; r < 4; ++r) {
    float v = lr[r];
    v += __shfl_xor(v, 1);
    v += __shfl_xor(v, 2);
    v += __shfl_xor(v, 4);
    v += __shfl_xor(v, 8);
    lr[r] = v;
  }

  short* base = pidx < 216 ? OpA + (size_t)pidx * 32768 : OpB + (size_t)(pidx - 216) * 32768;
  const int lrow0 = wv * 16 + quad * 4;
#pragma unroll
  for (int cn = 0; cn < 32; ++cn) {
    const int col = cn * 16 + cl;
#pragma unroll
    for (int r = 0; r < 4; ++r)
      base[(size_t)(lrow0 + r) * 512 + col] = f2bf(o[cn][r]);
  }
  if (cl == 0) {
#pragma unroll
    for (int r = 0; r < 4; ++r) Lp[pidx * 64 + lrow0 + r] = lr[r];
  }
}

// ---------------- attention combine: merge up to 8 chunk partials ----------------
__global__ __launch_bounds__(256) void attn_combine(const short* __restrict__ OpA,
                                                    const short* __restrict__ OpB,
                                                    const float* __restrict__ Lp,
                                                    short* __restrict__ O) {
  const int tid = threadIdx.x;
  const int wv = tid >> 6, lane = tid & 63;
  const int row = (int)blockIdx.x * 4 + wv;
  const int f = row >> 10, n = f + 1;
  const int qb = (row >> 6) & 15, lrow = row & 63;
  const int tri = f * (f + 1) / 2;
  float den = 0.f, acc[8];
#pragma unroll
  for (int i = 0; i < 8; ++i) acc[i] = 0.f;
#pragma unroll
  for (int ch = 0; ch < 8; ++ch) {
    if (ch < n) {
      const int pidx = (tri + ch) * 16 + qb;
      den += Lp[pidx * 64 + lrow];
      const short* b = pidx < 216 ? OpA + (size_t)pidx * 32768 : OpB + (size_t)(pidx - 216) * 32768;
      const short8 v = *(const short8*)(b + (size_t)lrow * 512 + lane * 8);
#pragma unroll
      for (int i = 0; i < 8; ++i) acc[i] += bf2f(v[i]);
    }
  }
  const float inv = 1.f / den;
  short8 ov;
#pragma unroll
  for (int i = 0; i < 8; ++i) ov[i] = f2bf(acc[i] * inv);
  *(short8*)(O + (size_t)row * 512 + lane * 8) = ov;
}

// ---------------- host ----------------
extern "C" void kernel_launch(void* const* d_in, const int* in_sizes, int n_in,
                              void* d_out, int out_size, void* d_ws, size_t ws_size,
                              hipStream_t stream) {
  const float* x     = (const float*)d_in[0];
  const float* r1_g1 = (const float*)d_in[1];
  const float* r1_w1 = (const float*)d_in[2];
  const float* r1_b1 = (const float*)d_in[3];
  const float* r1_g2 = (const float*)d_in[4];
  const float* r1_w2 = (const float*)d_in[5];
  const float* r1_b2 = (const float*)d_in[6];
  const float* at_g  = (const float*)d_in[7];
  const float* q_w   = (const float*)d_in[8];
  const float* q_b   = (const float*)d_in[9];
  const float* k_w   = (const float*)d_in[10];
  const float* k_b   = (const float*)d_in[11];
  const float* v_w   = (const float*)d_in[12];
  const float* v_b   = (const float*)d_in[13];
  const float* p_w   = (const float*)d_in[14];
  const float* p_b   = (const float*)d_in[15];
  const float* r2_g1 = (const float*)d_in[16];
  const float* r2_w1 = (const float*)d_in[17];
  const float* r2_b1 = (const float*)d_in[18];
  const float* r2_g2 = (const float*)d_in[19];
  const float* r2_w2 = (const float*)d_in[20];
  const float* r2_b2 = (const float*)d_in[21];
  float* out = (float*)d_out;

  char* ws = (char*)d_ws;
  size_t off = 0;
  auto alloc = [&](size_t bytes) -> void* {
    void* p = ws + off;
    off = (off + bytes + 255) & ~(size_t)255;
    return p;
  };
  short* wT    = (short*)alloc(27ull * 512 * 512 * 2);      // 14.16 MB = 216 x 64KB attn partials
  short* wqkvT = (short*)alloc(1536ull * 512 * 2);
  short* pwT   = (short*)alloc(512ull * 512 * 2);
  short* Xp    = (short*)alloc(10ull * 34 * 34 * 512 * 2);  // padded act; Xp+Y = 360+ partials
  float* Y     = (float*)alloc(8192ull * 512 * 4);          // conv partial P2 (fp32)
  float* hA    = (float*)alloc(8192ull * 512 * 4);
  short* xn    = (short*)alloc(8192ull * 512 * 2);          // + Qb = conv partial P0 (fp32)
  short* Qb    = (short*)alloc(8192ull * 512 * 2);
  short* Ksw   = (short*)alloc(8192ull * 512 * 2);          // + Vsw = conv partial P1 (fp32)
  short* Vsw   = (short*)alloc(8192ull * 512 * 2);
  float* Lp    = (float*)alloc(576ull * 64 * 4);
  (void)ws_size; (void)in_sizes; (void)n_in; (void)out_size;

  short* OpA = wT;          // 216 partials of 64q x 512c bf16
  short* OpB = Xp;          // 360 partials (Xp+Y contiguous = 436 capacity)
  float* P0  = (float*)xn;  // xn+Qb contiguous = 16.78 MB fp32
  float* P1  = (float*)Ksw; // Ksw+Vsw contiguous
  float* P2  = Y;
  float* P3  = out;         // d_out reused as 4th split-K partial (in-place-safe)

  const dim3 b256(256);
  const dim3 b512(512);
  const dim3 convg(32, 2, 4);  // 256x256 tiles, split-K 4 -> 256 blocks = 1/CU

  // ----- resnet 1 -----
  transpose_w<<<dim3(432, 16), b256, 0, stream>>>(r1_w1, wT, 13824, 512);
  norm_kernel<true, true><<<2890, b256, 0, stream>>>(x, r1_g1, Xp);
  conv_gemm8<<<convg, b512, 0, stream>>>(Xp, wT, P0, P1, P2, P3);
  transpose_w<<<dim3(432, 16), b256, 0, stream>>>(r1_w2, wT, 13824, 512);
  combine_norm<<<2890, b256, 0, stream>>>(P0, P1, P2, P3, r1_b1, r1_g2, Xp);
  conv_gemm8<<<convg, b512, 0, stream>>>(Xp, wT, P0, P1, P2, P3);
  conv_combine<true><<<4096, b256, 0, stream>>>(P0, P1, P2, P3, r1_b2, x, hA);

  // ----- attention -----
  norm_kernel<false, false><<<2048, b256, 0, stream>>>(hA, at_g, xn);
  transpose_w<<<dim3(16, 16), b256, 0, stream>>>(q_w, wqkvT, 512, 512);
  transpose_w<<<dim3(16, 16), b256, 0, stream>>>(k_w, wqkvT + 512 * 512, 512, 512);
  transpose_w<<<dim3(16, 16), b256, 0, stream>>>(v_w, wqkvT + 1024 * 512, 512, 512);
  transpose_w<<<dim3(16, 16), b256, 0, stream>>>(p_w, pwT, 512, 512);
  gemm_bt<0><<<dim3(64, 12), b256, 0, stream>>>(xn, wqkvT, 512, q_b, k_b, v_b,
                                                Qb, Ksw, Vsw, nullptr, nullptr);
  attn_partial<<<576, b256, 0, stream>>>(Qb, Ksw, Vsw, OpA, OpB, Lp);
  attn_combine<<<2048, b256, 0, stream>>>(OpA, OpB, Lp, xn);
  gemm_bt<1><<<dim3(64, 4), b256, 0, stream>>>(xn, pwT, 512, p_b, nullptr, nullptr,
                                               nullptr, nullptr, nullptr, hA, hA);

  // ----- resnet 2 -----
  transpose_w<<<dim3(432, 16), b256, 0, stream>>>(r2_w1, wT, 13824, 512);
  norm_kernel<true, true><<<2890, b256, 0, stream>>>(hA, r2_g1, Xp);
  conv_gemm8<<<convg, b512, 0, stream>>>(Xp, wT, P0, P1, P2, P3);
  transpose_w<<<dim3(432, 16), b256, 0, stream>>>(r2_w2, wT, 13824, 512);
  combine_norm<<<2890, b256, 0, stream>>>(P0, P1, P2, P3, r2_b1, r2_g2, Xp);
  conv_gemm8<<<convg, b512, 0, stream>>>(Xp, wT, P0, P1, P2, P3);
  conv_combine<true><<<4096, b256, 0, stream>>>(P0, P1, P2, P3, r2_b2, hA, out);
}

// Round 7
// 924.676 us; speedup vs baseline: 1.2836x; 1.2836x over previous
//
#include <hip/hip_runtime.h>
#include <cstdint>
#include <cstddef>

// ---------------- types & helpers ----------------
typedef __attribute__((ext_vector_type(4))) float floatx4;
typedef __attribute__((ext_vector_type(8))) short short8;

__device__ __forceinline__ short f2bf(float x) {
  union { float f; unsigned u; } c; c.f = x;
  unsigned r = (c.u + 0x7FFFu + ((c.u >> 16) & 1u)) >> 16;  // RNE
  return (short)r;
}

__device__ __forceinline__ float bf2f(short x) {
  union { unsigned u; float f; } c; c.u = ((unsigned)(unsigned short)x) << 16;
  return c.f;
}

__device__ __forceinline__ floatx4 mfma16(short8 a, short8 b, floatx4 c) {
  return __builtin_amdgcn_mfma_f32_16x16x32_bf16(a, b, c, 0, 0, 0);
}

// async global->LDS, 16B per lane; LDS dest is wave-uniform base + lane*16
template <typename T>
__device__ __forceinline__ void gl_lds16(const T* g, T* l) {
  __builtin_amdgcn_global_load_lds(
      (__attribute__((address_space(1))) void*)g,
      (__attribute__((address_space(3))) void*)l, 16, 0, 0);
}

#define MEMFENCE asm volatile("" ::: "memory")
#define WAITV8 asm volatile("s_waitcnt vmcnt(8)" ::: "memory")
#define WAITV2 asm volatile("s_waitcnt vmcnt(2)" ::: "memory")
#define WAITV0 asm volatile("s_waitcnt vmcnt(0)" ::: "memory")

// ---------------- rmsnorm (+silu) with optional replicate-pad ----------------
template <bool PAD, bool SILU>
__global__ __launch_bounds__(256) void norm_kernel(const float* __restrict__ src,
                                                   const float* __restrict__ gamma,
                                                   short* __restrict__ dst) {
  const int tid = threadIdx.x;
  const int wv = tid >> 6, lane = tid & 63;
  const int id = blockIdx.x * 4 + wv;
  int srow;
  if (PAD) {
    int tp = id / 1156, rem = id - tp * 1156;
    int hp = rem / 34, wp = rem - hp * 34;
    int t = tp - 2; t = t < 0 ? 0 : t;
    int h = hp - 1; h = h < 0 ? 0 : (h > 31 ? 31 : h);
    int w = wp - 1; w = w < 0 ? 0 : (w > 31 ? 31 : w);
    srow = (t << 10) + (h << 5) + w;
  } else {
    srow = id;
  }
  const float* sp = src + (size_t)srow * 512 + lane * 8;
  float4 v0 = *(const float4*)sp;
  float4 v1 = *(const float4*)(sp + 4);
  float a[8] = {v0.x, v0.y, v0.z, v0.w, v1.x, v1.y, v1.z, v1.w};
  float ss = 0.f;
#pragma unroll
  for (int i = 0; i < 8; ++i) ss += a[i] * a[i];
#pragma unroll
  for (int off = 32; off > 0; off >>= 1) ss += __shfl_xor(ss, off);
  const float scale = 22.627416997969522f / (sqrtf(ss) + 1e-8f);  // sqrt(512)/(||x||+eps)
  const float* gp = gamma + lane * 8;
  float4 g0 = *(const float4*)gp;
  float4 g1 = *(const float4*)(gp + 4);
  float g[8] = {g0.x, g0.y, g0.z, g0.w, g1.x, g1.y, g1.z, g1.w};
  short8 ov;
#pragma unroll
  for (int i = 0; i < 8; ++i) {
    float y = a[i] * scale * g[i];
    if (SILU) y = y / (1.f + __expf(-y));
    ov[i] = f2bf(y);
  }
  *(short8*)(dst + (size_t)id * 512 + lane * 8) = ov;
}

// ---------------- fused split-K combine (4 partials) + rmsnorm + silu + replicate-pad ----------------
__global__ __launch_bounds__(256) void combine_norm(const float* __restrict__ P0,
                                                    const float* __restrict__ P1,
                                                    const float* __restrict__ P2,
                                                    const float* __restrict__ P3,
                                                    const float* __restrict__ bias,
                                                    const float* __restrict__ gamma,
                                                    short* __restrict__ dst) {
  const int tid = threadIdx.x;
  const int wv = tid >> 6, lane = tid & 63;
  const int id = blockIdx.x * 4 + wv;
  int tp = id / 1156, rem = id - tp * 1156;
  int hp = rem / 34, wp = rem - hp * 34;
  int t = tp - 2; t = t < 0 ? 0 : t;
  int h = hp - 1; h = h < 0 ? 0 : (h > 31 ? 31 : h);
  int w = wp - 1; w = w < 0 ? 0 : (w > 31 ? 31 : w);
  const size_t base = (size_t)((t << 10) + (h << 5) + w) * 512 + lane * 8;
  float a[8];
  {
    float4 a0 = *(const float4*)(P0 + base), a1 = *(const float4*)(P0 + base + 4);
    float4 b0 = *(const float4*)(P1 + base), b1 = *(const float4*)(P1 + base + 4);
    float4 c0 = *(const float4*)(P2 + base), c1 = *(const float4*)(P2 + base + 4);
    float4 d0 = *(const float4*)(P3 + base), d1 = *(const float4*)(P3 + base + 4);
    float4 z0 = *(const float4*)(bias + lane * 8), z1 = *(const float4*)(bias + lane * 8 + 4);
    a[0] = a0.x + b0.x + c0.x + d0.x + z0.x;
    a[1] = a0.y + b0.y + c0.y + d0.y + z0.y;
    a[2] = a0.z + b0.z + c0.z + d0.z + z0.z;
    a[3] = a0.w + b0.w + c0.w + d0.w + z0.w;
    a[4] = a1.x + b1.x + c1.x + d1.x + z1.x;
    a[5] = a1.y + b1.y + c1.y + d1.y + z1.y;
    a[6] = a1.z + b1.z + c1.z + d1.z + z1.z;
    a[7] = a1.w + b1.w + c1.w + d1.w + z1.w;
  }
  float ss = 0.f;
#pragma unroll
  for (int i = 0; i < 8; ++i) ss += a[i] * a[i];
#pragma unroll
  for (int off = 32; off > 0; off >>= 1) ss += __shfl_xor(ss, off);
  const float scale = 22.627416997969522f / (sqrtf(ss) + 1e-8f);
  float4 g0 = *(const float4*)(gamma + lane * 8), g1 = *(const float4*)(gamma + lane * 8 + 4);
  float g[8] = {g0.x, g0.y, g0.z, g0.w, g1.x, g1.y, g1.z, g1.w};
  short8 ov;
#pragma unroll
  for (int i = 0; i < 8; ++i) {
    float y = a[i] * scale * g[i];
    y = y / (1.f + __expf(-y));
    ov[i] = f2bf(y);
  }
  *(short8*)(dst + (size_t)id * 512 + lane * 8) = ov;
}

// ---------------- weight transpose fp32 [R][C] -> bf16 [C][R] ----------------
__global__ __launch_bounds__(256) void transpose_w(const float* __restrict__ src,
                                                   short* __restrict__ dst, int R, int C) {
  __shared__ float t[32][33];
  const int tx = threadIdx.x & 31, ty = threadIdx.x >> 5;
  const int r0 = (int)blockIdx.x << 5, c0 = (int)blockIdx.y << 5;
#pragma unroll
  for (int i = 0; i < 4; ++i)
    t[ty + i * 8][tx] = src[(size_t)(r0 + ty + i * 8) * C + c0 + tx];
  __syncthreads();
#pragma unroll
  for (int i = 0; i < 4; ++i)
    dst[(size_t)(c0 + ty + i * 8) * R + r0 + tx] = f2bf(t[tx][ty + i * 8]);
}

// ---------------- implicit-GEMM causal conv3d: 256x256 tile, 8 waves, 4-phase ----------------
// split-K 4 -> grid (32,2,4) = 256 blocks = 1/CU, no tail. BK=64, dbuf LDS 128KB.
// Barrier-minimal schedule (2 per K-step, was 8):
//   p0: issue 2 loads(t+1->buf^1); WAITV2; BARRIER (publishes buf; also the only
//       sync needed before overwriting buf at t+1 is the END barrier below);
//   p1..p3: issue 2 loads each; ds_read + 16 MFMA, no barriers (reads target buf,
//       writes target buf^1 -> no intra-step hazard);
//   p3 end: BARRIER (all waves done reading buf before t+1 stages into it... and
//       before t+1 overwrites buf^1's reader epoch). vmcnt counted, never 0 in-loop.
// Slot XOR-swizzle vs row (both-sides involution via pre-permuted global source).
__global__ __launch_bounds__(512, 2) void conv_gemm8(const short* __restrict__ Xp,
                                                     const short* __restrict__ WT,
                                                     float* __restrict__ P0,
                                                     float* __restrict__ P1,
                                                     float* __restrict__ P2,
                                                     float* __restrict__ P3) {
  __shared__ __attribute__((aligned(16))) short Alds[2][16384];
  __shared__ __attribute__((aligned(16))) short Blds[2][16384];
  const int tid = threadIdx.x;
  const int wid = tid >> 6, lane = tid & 63;
  const int m0 = (int)blockIdx.x << 8, n0 = (int)blockIdx.y << 8;
  const int z = blockIdx.z;
  float* __restrict__ dst = z == 0 ? P0 : (z == 1 ? P1 : (z == 2 ? P2 : P3));
  const int wm = (wid >> 2) << 7, wn = (wid & 3) << 6;  // wave 2M x 4N -> 128x64 out

  // staging constants: thread covers (row = part*64 + tid/8, phys slot = tid&7);
  // fetch logical ch-slot = phys ^ (row&7)
  const int logslot = (tid & 7) ^ ((tid >> 3) & 7);
  int aoffA[4], boffB[4];
#pragma unroll
  for (int q = 0; q < 4; ++q) {
    const int m = m0 + q * 64 + (tid >> 3);
    const int t = m >> 10, h = (m >> 5) & 31, w = m & 31;
    aoffA[q] = (t * 1156 + h * 34 + w) * 512 + logslot * 8;
    boffB[q] = (n0 + q * 64 + (tid >> 3)) * 13824 + logslot * 8;
  }
  const int lwb = wid * 512;  // per-wave LDS dest offset (shorts) within a part

  // frag-read constants: row = base + (lane&15); phys slot = logical ^ (lane&7)
  const int frow = lane & 15;
  const int fslot = lane >> 4;  // 0..3
  const int sx = lane & 7;

  floatx4 acc[4][2][4];
#pragma unroll
  for (int p = 0; p < 4; ++p)
#pragma unroll
    for (int i = 0; i < 2; ++i)
#pragma unroll
      for (int j = 0; j < 4; ++j) acc[p][i][j] = 0.f;

  const int k0g = z * 54;  // 216 K-steps of 64 over 27 taps x 512cin, split 4

  auto tapoff_of = [&](int kkg) {
    const int tap = kkg >> 3;
    const int dt = tap / 9;
    const int r9 = tap - dt * 9;
    const int dh = r9 / 3;
    const int dw = r9 - dh * 3;
    return (dt * 1156 + dh * 34 + dw) * 512 + ((kkg & 7) << 6);
  };

  // prologue: stage all 8 parts of step 0
  {
    const int to = tapoff_of(k0g);
#pragma unroll
    for (int q = 0; q < 4; ++q) {
      gl_lds16(Xp + aoffA[q] + to, &Alds[0][q * 4096 + lwb]);
      gl_lds16(WT + boffB[q] + (k0g << 6), &Blds[0][q * 4096 + lwb]);
    }
  }

  for (int kk = 0; kk < 54; ++kk) {
    const int buf = kk & 1;
    const bool nx = (kk + 1 < 54);
    const int kng = k0g + kk + 1;
    const int ton = nx ? tapoff_of(kng) : 0;
    short8 bfr[4][2];
#pragma unroll
    for (int p = 0; p < 4; ++p) {
      if (p == 0) {
        if (nx) {
          gl_lds16(Xp + aoffA[0] + ton, &Alds[buf ^ 1][lwb]);
          gl_lds16(Xp + aoffA[1] + ton, &Alds[buf ^ 1][4096 + lwb]);
          WAITV2;  // retire this step's 8 loads; keep 2 in flight
        } else {
          WAITV0;
        }
        MEMFENCE;
        __builtin_amdgcn_s_barrier();  // publish buf (only entry barrier)
        MEMFENCE;
#pragma unroll
        for (int fj = 0; fj < 4; ++fj)
#pragma unroll
          for (int ks = 0; ks < 2; ++ks) {
            const int row = wn + fj * 16 + frow;
            bfr[fj][ks] =
                *(const short8*)&Blds[buf][row * 64 + (((ks << 2) + fslot) ^ sx) * 8];
          }
      } else if (nx) {
        if (p == 1) {
          gl_lds16(Xp + aoffA[2] + ton, &Alds[buf ^ 1][8192 + lwb]);
          gl_lds16(Xp + aoffA[3] + ton, &Alds[buf ^ 1][12288 + lwb]);
        } else if (p == 2) {
          gl_lds16(WT + boffB[0] + (kng << 6), &Blds[buf ^ 1][lwb]);
          gl_lds16(WT + boffB[1] + (kng << 6), &Blds[buf ^ 1][4096 + lwb]);
        } else {
          gl_lds16(WT + boffB[2] + (kng << 6), &Blds[buf ^ 1][8192 + lwb]);
          gl_lds16(WT + boffB[3] + (kng << 6), &Blds[buf ^ 1][12288 + lwb]);
        }
      }
      short8 afr[2][2];
#pragma unroll
      for (int fi = 0; fi < 2; ++fi)
#pragma unroll
        for (int ks = 0; ks < 2; ++ks) {
          const int row = wm + p * 32 + fi * 16 + frow;
          afr[fi][ks] =
              *(const short8*)&Alds[buf][row * 64 + (((ks << 2) + fslot) ^ sx) * 8];
        }
      __builtin_amdgcn_s_setprio(1);
#pragma unroll
      for (int fi = 0; fi < 2; ++fi)
#pragma unroll
        for (int fj = 0; fj < 4; ++fj)
#pragma unroll
          for (int ks = 0; ks < 2; ++ks)
            acc[p][fi][fj] = mfma16(afr[fi][ks], bfr[fj][ks], acc[p][fi][fj]);
      __builtin_amdgcn_s_setprio(0);
      if (p == 3) {  // end-of-step: all waves done reading buf
        MEMFENCE;
        __builtin_amdgcn_s_barrier();
        MEMFENCE;
      }
    }
  }

  // epilogue: C/D mapping col = lane&15, row = (lane>>4)*4 + r
#pragma unroll
  for (int p = 0; p < 4; ++p)
#pragma unroll
    for (int fi = 0; fi < 2; ++fi) {
      const int rb = m0 + wm + p * 32 + fi * 16 + (lane >> 4) * 4;
#pragma unroll
      for (int fj = 0; fj < 4; ++fj) {
        const int col = n0 + wn + fj * 16 + (lane & 15);
#pragma unroll
        for (int r = 0; r < 4; ++r)
          dst[(size_t)(rb + r) * 512 + col] = acc[p][fi][fj][r];
      }
    }
}

template <bool HAS_RES>
__global__ __launch_bounds__(256) void conv_combine(const float* __restrict__ P0,
                                                    const float* __restrict__ P1,
                                                    const float* __restrict__ P2,
                                                    const float* __restrict__ P3,
                                                    const float* __restrict__ bias,
                                                    const float* __restrict__ res,
                                                    float* __restrict__ out) {
  const size_t i = ((size_t)blockIdx.x * 256 + threadIdx.x) * 4;
  float4 a = *(const float4*)(P0 + i);
  float4 b = *(const float4*)(P1 + i);
  float4 c = *(const float4*)(P2 + i);
  float4 d = *(const float4*)(P3 + i);
  float4 bz = *(const float4*)(bias + (int)(i & 511));
  float4 r;
  r.x = a.x + b.x + c.x + d.x + bz.x;
  r.y = a.y + b.y + c.y + d.y + bz.y;
  r.z = a.z + b.z + c.z + d.z + bz.z;
  r.w = a.w + b.w + c.w + d.w + bz.w;
  if (HAS_RES) {
    float4 rs = *(const float4*)(res + i);
    r.x += rs.x; r.y += rs.y; r.z += rs.z; r.w += rs.w;
  }
  *(float4*)(out + i) = r;
}

// ---------------- generic GEMM  C = A(MxK) * BT(NxK)^T, dbuf prefetch ----------------
// Slot-XOR LDS swizzle (R2). EPI=0: QKV — Q row-major bf16; K,V pre-swizzled:
//   K tile offset(key,c) = (c>>5)*1024 + ((c>>3)&3)*256 + key*8 + (c&7)
//   V tile offset(key,c) = ((key>>3)&3)*4096 + c*8 + (key&7)
// EPI=1: fp32 out = acc + bias + res (proj + identity; in-place-safe).
template <int EPI>
__global__ __launch_bounds__(256) void gemm_bt(const short* __restrict__ A,
                                               const short* __restrict__ BT, int kdim,
                                               const float* __restrict__ b0,
                                               const float* __restrict__ b1,
                                               const float* __restrict__ b2,
                                               short* __restrict__ o0,
                                               short* __restrict__ o1,
                                               short* __restrict__ o2,
                                               float* oF, const float* res) {
  __shared__ __attribute__((aligned(16))) short Alds[2][4096];
  __shared__ __attribute__((aligned(16))) short Blds[2][4096];
  const int tid = threadIdx.x;
  const int wv = tid >> 6, lane = tid & 63;
  const int m0 = (int)blockIdx.x << 7, n0 = (int)blockIdx.y << 7;
  const int swz = (((lane & 3) ^ ((lane >> 3) & 3)) << 3);
  int aoff[2], boff[2];
#pragma unroll
  for (int j = 0; j < 2; ++j) {
    const int chunk = wv * 2 + j;
    aoff[j] = (m0 + chunk * 16 + (lane >> 2)) * kdim + swz;
    boff[j] = (n0 + chunk * 16 + (lane >> 2)) * kdim + swz;
  }
  const int wm = (wv & 1) << 6, wn = (wv >> 1) << 6;
  floatx4 acc[4][4];
#pragma unroll
  for (int i = 0; i < 4; ++i)
#pragma unroll
    for (int j = 0; j < 4; ++j) acc[i][j] = 0.f;
  const int la = (lane & 15) * 32 + ((((lane >> 4) ^ ((lane >> 1) & 3))) << 3);
  const int kiters = kdim >> 5;

  auto stage = [&](int kk, int buf) {
#pragma unroll
    for (int j = 0; j < 2; ++j) {
      const int chunk = wv * 2 + j;
      gl_lds16(A + aoff[j] + (kk << 5), &Alds[buf][chunk * 512]);
      gl_lds16(BT + boff[j] + (kk << 5), &Blds[buf][chunk * 512]);
    }
  };

  stage(0, 0);
  for (int kk = 0; kk < kiters; ++kk) {
    const int cur = kk & 1;
    __syncthreads();
    if (kk + 1 < kiters) stage(kk + 1, cur ^ 1);
    short8 af[4], bf[4];
#pragma unroll
    for (int i = 0; i < 4; ++i) af[i] = *(const short8*)&Alds[cur][(wm + i * 16) * 32 + la];
#pragma unroll
    for (int j = 0; j < 4; ++j) bf[j] = *(const short8*)&Blds[cur][(wn + j * 16) * 32 + la];
#pragma unroll
    for (int i = 0; i < 4; ++i)
#pragma unroll
      for (int j = 0; j < 4; ++j) acc[i][j] = mfma16(af[i], bf[j], acc[i][j]);
  }

  const int rbase = m0 + wm + (lane >> 4) * 4;
#pragma unroll
  for (int i = 0; i < 4; ++i) {
    const int row = rbase + i * 16;
#pragma unroll
    for (int j = 0; j < 4; ++j) {
      const int col = n0 + wn + j * 16 + (lane & 15);
      if (EPI == 0) {
        const int sel = col >> 9;
        const int c = col & 511;
        const float* bp = sel == 0 ? b0 : (sel == 1 ? b1 : b2);
        const float bz = bp[c];
#pragma unroll
        for (int r = 0; r < 4; ++r) {
          const int rr = row + r;
          const short v = f2bf(acc[i][j][r] + bz);
          if (sel == 0) {
            o0[(size_t)rr * 512 + c] = v;
          } else if (sel == 1) {
            o1[(size_t)(rr >> 5) * 16384 + ((c >> 5) << 10) + (((c >> 3) & 3) << 8) +
               ((rr & 31) << 3) + (c & 7)] = v;
          } else {
            o2[(size_t)(rr >> 5) * 16384 + (((rr >> 3) & 3) << 12) + (c << 3) + (rr & 7)] = v;
          }
        }
      } else {
        const float bz = b0[col];
#pragma unroll
        for (int r = 0; r < 4; ++r) {
          const size_t idx = (size_t)(row + r) * 512 + col;
          oF[idx] = acc[i][j][r] + bz + res[idx];
        }
      }
    }
  }
}

// ---------------- split-K flash attention partials (R4 version — reverted) ----------------
// block = 256 thr (4 waves) = 64 q x one 1024-key chunk; grid 576 @ 2 blocks/CU.
// NOTE (R5 lesson): this kernel's speed depends on same-y blocks staying in
// lockstep and sharing K/V tiles via XCD L2 (fetch 59 MB vs 1.15 GB logical).
// The 3-block/CU LDS-diet variant desynced blocks -> 12x fetch, 2.2x slower.
__global__ __launch_bounds__(256, 2) void attn_partial(const short* __restrict__ Q,
                                                       const short* __restrict__ Ksw,
                                                       const short* __restrict__ Vsw,
                                                       short* __restrict__ OpA,
                                                       short* __restrict__ OpB,
                                                       float* __restrict__ Lp) {
  __shared__ __attribute__((aligned(16))) short Klds[16384];
  __shared__ __attribute__((aligned(16))) short Vlds[16384];
  __shared__ __attribute__((aligned(16))) short Plds[4][512];
  const int tid = threadIdx.x;
  const int wv = tid >> 6, lane = tid & 63;
  const int cl = lane & 15, quad = lane >> 4;
  // XCD-clustered mapping: xcd = bid & 7 (HW round-robin heuristic).
  const int bid = (int)blockIdx.x;
  const int x8 = bid & 7, jj = bid >> 3;
  int y, qb;
  if (jj < 64) {
    y = x8 + ((jj >> 4) << 3);
    qb = jj & 15;
  } else {
    const int L = x8 * 8 + (jj - 64);
    y = 32 + (L >> 4);
    qb = L & 15;
  }
  int f = 0;
  while ((f + 1) * (f + 2) / 2 <= y) ++f;
  const int chunk = y - f * (f + 1) / 2;
  const int pidx = y * 16 + qb;
  const int q0 = (f << 10) + (qb << 6);

  short8 qf[16];
  {
    const short* qp = Q + (size_t)(q0 + wv * 16 + cl) * 512 + quad * 8;
#pragma unroll
    for (int kc = 0; kc < 16; ++kc) qf[kc] = *(const short8*)(qp + kc * 32);
  }
  floatx4 o[32];
#pragma unroll
  for (int i = 0; i < 32; ++i) o[i] = 0.f;
  float lr[4] = {0.f, 0.f, 0.f, 0.f};
  const float c1 = 0.063758716f;  // log2(e)/sqrt(512)
  const short* klb = Klds + quad * 256 + cl * 8;
  const short* vlb = Vlds + quad * 4096 + cl * 8;
  const int swr = ((cl >> 1) & 3) << 3;

  auto stageK = [&](int kt) {
    const size_t tb = (size_t)((chunk << 5) + kt) * 16384;
#pragma unroll
    for (int j = 0; j < 8; ++j) {
      const int row = (j * 4 + wv) << 9;
      gl_lds16(Ksw + tb + row + lane * 8, &Klds[row]);
    }
  };
  auto stageV = [&](int kt) {
    const size_t tb = (size_t)((chunk << 5) + kt) * 16384;
#pragma unroll
    for (int j = 0; j < 8; ++j) {
      const int row = (j * 4 + wv) << 9;
      gl_lds16(Vsw + tb + row + lane * 8, &Vlds[row]);
    }
  };

  // prologue: 16 loads in flight (8 K, 8 V per wave)
  stageK(0);
  stageV(0);

  for (int kt = 0; kt < 32; ++kt) {
    // K(kt) ready: per-wave vmcnt(8) retires the 8 oldest (K) loads; barrier
    // publishes all waves' K writes. V(kt) may still be in flight.
    WAITV8;
    __builtin_amdgcn_s_barrier();
    MEMFENCE;

    floatx4 s0 = 0.f, s1 = 0.f;
    __builtin_amdgcn_s_setprio(1);
#pragma unroll
    for (int kc = 0; kc < 16; ++kc) {
      short8 k0 = *(const short8*)(klb + kc * 1024);
      short8 k1 = *(const short8*)(klb + kc * 1024 + 128);
      s0 = mfma16(qf[kc], k0, s0);
      s1 = mfma16(qf[kc], k1, s1);
    }
    __builtin_amdgcn_s_setprio(0);

    MEMFENCE;
    __builtin_amdgcn_s_barrier();  // all waves done reading Klds
    MEMFENCE;
    if (kt + 1 < 32) stageK(kt + 1);  // flies under softmax + PV

#pragma unroll
    for (int r = 0; r < 4; ++r) {
      const float p0 = exp2f(s0[r] * c1), p1 = exp2f(s1[r] * c1);
      lr[r] += p0 + p1;  // per-lane partial; row-sum deferred to epilogue
      const int qlr = quad * 4 + r;
      const int sw = ((qlr >> 1) & 3) << 3;
      const int oi = qlr * 32 + (cl ^ sw);
      Plds[wv][oi] = f2bf(p0);
      Plds[wv][oi ^ 16] = f2bf(p1);
    }

    // V(kt) ready: outstanding = V(kt) remainder + K(kt+1); vmcnt(8) retires V.
    WAITV8;
    __builtin_amdgcn_s_barrier();
    MEMFENCE;

    const short8 pf = *(const short8*)&Plds[wv][cl * 32 + ((quad << 3) ^ swr)];
    __builtin_amdgcn_s_setprio(1);
#pragma unroll
    for (int cn = 0; cn < 32; ++cn) {
      const short8 vf = *(const short8*)(vlb + cn * 128);
      o[cn] = mfma16(pf, vf, o[cn]);
    }
    __builtin_amdgcn_s_setprio(0);

    MEMFENCE;
    __builtin_amdgcn_s_barrier();  // all waves done reading Vlds
    MEMFENCE;
    if (kt + 1 < 32) stageV(kt + 1);  // flies under next QK
  }

#pragma unroll
  for (int r = 0; r < 4; ++r) {
    float v = lr[r];
    v += __shfl_xor(v, 1);
    v += __shfl_xor(v, 2);
    v += __shfl_xor(v, 4);
    v += __shfl_xor(v, 8);
    lr[r] = v;
  }

  short* base = pidx < 216 ? OpA + (size_t)pidx * 32768 : OpB + (size_t)(pidx - 216) * 32768;
  const int lrow0 = wv * 16 + quad * 4;
#pragma unroll
  for (int cn = 0; cn < 32; ++cn) {
    const int col = cn * 16 + cl;
#pragma unroll
    for (int r = 0; r < 4; ++r)
      base[(size_t)(lrow0 + r) * 512 + col] = f2bf(o[cn][r]);
  }
  if (cl == 0) {
#pragma unroll
    for (int r = 0; r < 4; ++r) Lp[pidx * 64 + lrow0 + r] = lr[r];
  }
}

// ---------------- attention combine: merge up to 8 chunk partials ----------------
__global__ __launch_bounds__(256) void attn_combine(const short* __restrict__ OpA,
                                                    const short* __restrict__ OpB,
                                                    const float* __restrict__ Lp,
                                                    short* __restrict__ O) {
  const int tid = threadIdx.x;
  const int wv = tid >> 6, lane = tid & 63;
  const int row = (int)blockIdx.x * 4 + wv;
  const int f = row >> 10, n = f + 1;
  const int qb = (row >> 6) & 15, lrow = row & 63;
  const int tri = f * (f + 1) / 2;
  float den = 0.f, acc[8];
#pragma unroll
  for (int i = 0; i < 8; ++i) acc[i] = 0.f;
#pragma unroll
  for (int ch = 0; ch < 8; ++ch) {
    if (ch < n) {
      const int pidx = (tri + ch) * 16 + qb;
      den += Lp[pidx * 64 + lrow];
      const short* b = pidx < 216 ? OpA + (size_t)pidx * 32768 : OpB + (size_t)(pidx - 216) * 32768;
      const short8 v = *(const short8*)(b + (size_t)lrow * 512 + lane * 8);
#pragma unroll
      for (int i = 0; i < 8; ++i) acc[i] += bf2f(v[i]);
    }
  }
  const float inv = 1.f / den;
  short8 ov;
#pragma unroll
  for (int i = 0; i < 8; ++i) ov[i] = f2bf(acc[i] * inv);
  *(short8*)(O + (size_t)row * 512 + lane * 8) = ov;
}

// ---------------- host ----------------
extern "C" void kernel_launch(void* const* d_in, const int* in_sizes, int n_in,
                              void* d_out, int out_size, void* d_ws, size_t ws_size,
                              hipStream_t stream) {
  const float* x     = (const float*)d_in[0];
  const float* r1_g1 = (const float*)d_in[1];
  const float* r1_w1 = (const float*)d_in[2];
  const float* r1_b1 = (const float*)d_in[3];
  const float* r1_g2 = (const float*)d_in[4];
  const float* r1_w2 = (const float*)d_in[5];
  const float* r1_b2 = (const float*)d_in[6];
  const float* at_g  = (const float*)d_in[7];
  const float* q_w   = (const float*)d_in[8];
  const float* q_b   = (const float*)d_in[9];
  const float* k_w   = (const float*)d_in[10];
  const float* k_b   = (const float*)d_in[11];
  const float* v_w   = (const float*)d_in[12];
  const float* v_b   = (const float*)d_in[13];
  const float* p_w   = (const float*)d_in[14];
  const float* p_b   = (const float*)d_in[15];
  const float* r2_g1 = (const float*)d_in[16];
  const float* r2_w1 = (const float*)d_in[17];
  const float* r2_b1 = (const float*)d_in[18];
  const float* r2_g2 = (const float*)d_in[19];
  const float* r2_w2 = (const float*)d_in[20];
  const float* r2_b2 = (const float*)d_in[21];
  float* out = (float*)d_out;

  char* ws = (char*)d_ws;
  size_t off = 0;
  auto alloc = [&](size_t bytes) -> void* {
    void* p = ws + off;
    off = (off + bytes + 255) & ~(size_t)255;
    return p;
  };
  short* wT    = (short*)alloc(27ull * 512 * 512 * 2);      // 14.16 MB = 216 x 64KB attn partials
  short* wqkvT = (short*)alloc(1536ull * 512 * 2);
  short* pwT   = (short*)alloc(512ull * 512 * 2);
  short* Xp    = (short*)alloc(10ull * 34 * 34 * 512 * 2);  // padded act; Xp+Y = 360+ partials
  float* Y     = (float*)alloc(8192ull * 512 * 4);          // conv partial P2 (fp32)
  float* hA    = (float*)alloc(8192ull * 512 * 4);
  short* xn    = (short*)alloc(8192ull * 512 * 2);          // + Qb = conv partial P0 (fp32)
  short* Qb    = (short*)alloc(8192ull * 512 * 2);
  short* Ksw   = (short*)alloc(8192ull * 512 * 2);          // + Vsw = conv partial P1 (fp32)
  short* Vsw   = (short*)alloc(8192ull * 512 * 2);
  float* Lp    = (float*)alloc(576ull * 64 * 4);
  (void)ws_size; (void)in_sizes; (void)n_in; (void)out_size;

  short* OpA = wT;          // 216 partials of 64q x 512c bf16
  short* OpB = Xp;          // 360 partials (Xp+Y contiguous = 436 capacity)
  float* P0  = (float*)xn;  // xn+Qb contiguous = 16.78 MB fp32
  float* P1  = (float*)Ksw; // Ksw+Vsw contiguous
  float* P2  = Y;
  float* P3  = out;         // d_out reused as 4th split-K partial (in-place-safe)

  const dim3 b256(256);
  const dim3 b512(512);
  const dim3 convg(32, 2, 4);  // 256x256 tiles, split-K 4 -> 256 blocks = 1/CU

  // ----- resnet 1 -----
  transpose_w<<<dim3(432, 16), b256, 0, stream>>>(r1_w1, wT, 13824, 512);
  norm_kernel<true, true><<<2890, b256, 0, stream>>>(x, r1_g1, Xp);
  conv_gemm8<<<convg, b512, 0, stream>>>(Xp, wT, P0, P1, P2, P3);
  transpose_w<<<dim3(432, 16), b256, 0, stream>>>(r1_w2, wT, 13824, 512);
  combine_norm<<<2890, b256, 0, stream>>>(P0, P1, P2, P3, r1_b1, r1_g2, Xp);
  conv_gemm8<<<convg, b512, 0, stream>>>(Xp, wT, P0, P1, P2, P3);
  conv_combine<true><<<4096, b256, 0, stream>>>(P0, P1, P2, P3, r1_b2, x, hA);

  // ----- attention -----
  norm_kernel<false, false><<<2048, b256, 0, stream>>>(hA, at_g, xn);
  transpose_w<<<dim3(16, 16), b256, 0, stream>>>(q_w, wqkvT, 512, 512);
  transpose_w<<<dim3(16, 16), b256, 0, stream>>>(k_w, wqkvT + 512 * 512, 512, 512);
  transpose_w<<<dim3(16, 16), b256, 0, stream>>>(v_w, wqkvT + 1024 * 512, 512, 512);
  transpose_w<<<dim3(16, 16), b256, 0, stream>>>(p_w, pwT, 512, 512);
  gemm_bt<0><<<dim3(64, 12), b256, 0, stream>>>(xn, wqkvT, 512, q_b, k_b, v_b,
                                                Qb, Ksw, Vsw, nullptr, nullptr);
  attn_partial<<<576, b256, 0, stream>>>(Qb, Ksw, Vsw, OpA, OpB, Lp);
  attn_combine<<<2048, b256, 0, stream>>>(OpA, OpB, Lp, xn);
  gemm_bt<1><<<dim3(64, 4), b256, 0, stream>>>(xn, pwT, 512, p_b, nullptr, nullptr,
                                               nullptr, nullptr, nullptr, hA, hA);

  // ----- resnet 2 -----
  transpose_w<<<dim3(432, 16), b256, 0, stream>>>(r2_w1, wT, 13824, 512);
  norm_kernel<true, true><<<2890, b256, 0, stream>>>(hA, r2_g1, Xp);
  conv_gemm8<<<convg, b512, 0, stream>>>(Xp, wT, P0, P1, P2, P3);
  transpose_w<<<dim3(432, 16), b256, 0, stream>>>(r2_w2, wT, 13824, 512);
  combine_norm<<<2890, b256, 0, stream>>>(P0, P1, P2, P3, r2_b1, r2_g2, Xp);
  conv_gemm8<<<convg, b512, 0, stream>>>(Xp, wT, P0, P1, P2, P3);
  conv_combine<true><<<4096, b256, 0, stream>>>(P0, P1, P2, P3, r2_b2, hA, out);
}